// Round 6
// baseline (3206.781 us; speedup 1.0000x reference)
//
#include <hip/hip_runtime.h>
#include <hip/hip_cooperative_groups.h>
#include <math.h>

namespace cg = cooperative_groups;

#define Bq 2
#define NEG 16
#define Nn 10000
#define Ee 80000
#define Dd 128
#define NUM_REL 237
#define Ll 3
#define K_SEL 1000
#define BN (Bq*Nn)
#define EPSV 1e-5f
#define MAXACT 2048
#define MAXTOUCH 8192
#define SELCAP 3328
#define LN2F 0.69314718056f
#define GRID 512
#define TPB  256

// ---------------- workspace layout (bytes) ----------------
constexpr size_t HID_OFF   = 0;                                   // BN*D f32
constexpr size_t SCORE_OFF = HID_OFF   + (size_t)BN*Dd*4;         // BN f32
constexpr size_t CVEC_OFF  = SCORE_OFF + (size_t)BN*4;            // B*D f32
constexpr size_t HDR_OFF   = CVEC_OFF  + (size_t)Bq*Dd*4;         // 64 i32
constexpr size_t THR_OFF   = HDR_OFF   + 64*4;                    // B u64
constexpr size_t SEL_OFF   = THR_OFF   + Bq*8;                    // BN u32 (fallback only)
constexpr size_t DEG_OFF   = SEL_OFF   + (size_t)BN*4;            // BN u32
constexpr size_t SLOT_OFF  = DEG_OFF   + (size_t)BN*4;            // BN i32
constexpr size_t CNT_OFF   = SLOT_OFF  + (size_t)BN*4;            // MAXACT u32
constexpr size_t SDEG_OFF  = CNT_OFF   + (size_t)MAXACT*4;        // MAXACT f32
constexpr size_t S1_OFF    = SDEG_OFF  + (size_t)MAXACT*4;        // MAXACT*D f32
constexpr size_t S2_OFF    = S1_OFF    + (size_t)MAXACT*Dd*4;
constexpr size_t MXB_OFF   = S2_OFF    + (size_t)MAXACT*Dd*4;     // MAXACT*D u32
constexpr size_t MNB_OFF   = MXB_OFF   + (size_t)MAXACT*Dd*4;
constexpr size_t TPART_OFF = MNB_OFF   + (size_t)MAXACT*Dd*4;     // 4*MAXACT*D f32
constexpr size_t ALIST_OFF = TPART_OFF + (size_t)4*MAXACT*Dd*4;   // MAXACT i32
constexpr size_t FLAG_OFF  = ALIST_OFF + (size_t)MAXACT*4;        // BN u32
constexpr size_t TLIST_OFF = FLAG_OFF  + (size_t)BN*4;            // MAXTOUCH i32
constexpr size_t EDGE_OFF  = TLIST_OFF + (size_t)MAXTOUCH*4;      // B*E*2 i32
constexpr size_t CTR_OFF   = EDGE_OFF  + (size_t)Bq*Ee*2*4;       // 16 u32
// ctr[0]=na ctr[1]=ne ctr[2]=log-sum f32bits ctr[3]=ntouched ctr[4]=sc0 bits
// ctr[5..6]=head scores bits  ctr[7]=hsrc ctr[8]=tsrc

// ---------------- helpers ----------------
__device__ __forceinline__ unsigned encf(float f){
  unsigned u = __float_as_uint(f);
  return (u & 0x80000000u) ? ~u : (u | 0x80000000u);
}
__device__ __forceinline__ float decf(unsigned e){
  unsigned u = (e & 0x80000000u) ? (e & 0x7FFFFFFFu) : ~e;
  return __uint_as_float(u);
}
__device__ __forceinline__ unsigned long long make_key(float f, int i){
  unsigned d = ~encf(f);
  return ((unsigned long long)d << 32) | (unsigned)i;
}
__device__ __forceinline__ unsigned ldv(const unsigned* p){
  return *(const volatile unsigned*)p;
}

// ---------------- shared-memory union (fused kernel) ----------------
struct SmSelect {
  unsigned sd[SELCAP];
  unsigned short sidx[SELCAP];
  unsigned hist[256];
  unsigned histT[256];
  unsigned wsum[4];
  int ntb;
  unsigned long long pref;
  unsigned kk;
};
struct SmScore { float sh[32*Dd]; float sx[32*Dd]; float sc[2*Dd]; float red[32*33]; int sv[32]; };
struct SmPost  { float lb[32*136]; float wbuf[3*16*64]; float sden[32]; unsigned shas[32]; };
struct SmResid { float tr[32*136]; float wbuf[16*64]; };
struct SmMsg   { float sd[4][Dd]; float ss[4][Dd]; int dsl[4]; };
struct SmPrep  { float relv[2][Dd]; float cv[2][Dd]; float hv[Dd]; float x[2][Dd]; float p[2][Dd];
                 int fh[2], ft[2], r0[2], hsrc, tsrc; };
union SmAll { SmSelect sel; SmScore sco; SmPost post; SmResid res; SmMsg msg; SmPrep prep; };

// ---------------- the fused cooperative kernel ----------------
// __launch_bounds__(256,2): min 2 waves/EU -> VGPR<=256 -> >=2 blocks/CU -> grid 512 fits.
__global__ __launch_bounds__(TPB, 2) void fused(
    const int* h_index, const int* r_index, const int* t_index,
    const float* hidden_states, const int* edge_index, const float* rel_embedding,
    const float* lin_W, const float* lin_b, const float* m1_W, const float* m1_b,
    const float* m2_W, const float* m2_b, const float* pre_W, const float* pre_b,
    const float* post_W, const float* post_b, const float* out_W, const float* out_b,
    char* ws, float* out)
{
  __shared__ SmAll SM;
  cg::grid_group grid = cg::this_grid();

  float*    hidden   = (float*)(ws + HID_OFF);
  float*    score    = (float*)(ws + SCORE_OFF);
  float*    cvec     = (float*)(ws + CVEC_OFF);
  int*      hdr      = (int*)(ws + HDR_OFF);
  unsigned long long* thr = (unsigned long long*)(ws + THR_OFF);
  unsigned* out_deg  = (unsigned*)(ws + DEG_OFF);
  int*      node_slot= (int*)(ws + SLOT_OFF);
  unsigned* cnt      = (unsigned*)(ws + CNT_OFF);
  float*    slot_deg = (float*)(ws + SDEG_OFF);
  float*    s1       = (float*)(ws + S1_OFF);
  float*    s2       = (float*)(ws + S2_OFF);
  unsigned* mxb      = (unsigned*)(ws + MXB_OFF);
  unsigned* mnb      = (unsigned*)(ws + MNB_OFF);
  float*    tpart    = (float*)(ws + TPART_OFF);
  int*      alist    = (int*)(ws + ALIST_OFF);
  unsigned* flag     = (unsigned*)(ws + FLAG_OFF);
  int*      tlist    = (int*)(ws + TLIST_OFF);
  int*      edges    = (int*)(ws + EDGE_OFF);
  unsigned* ctr      = (unsigned*)(ws + CTR_OFF);

  const int tid  = threadIdx.x;
  const int bid  = blockIdx.x;
  const int gth  = bid*TPB + tid;
  const int gstr = GRID*TPB;

  // sc0: identical serial order in every thread -> bit-identical everywhere
  float sc0 = m2_b[0];
  for (int k=0;k<Dd;k++) sc0 += fmaxf(m1_b[k],0.f)*m2_W[k];

  // ================= P0: zero hidden/flag, fill score, block0 prep =================
  {
    float4 z4 = make_float4(0.f,0.f,0.f,0.f);
    for (int i=gth; i<BN*Dd/4; i+=gstr) ((float4*)hidden)[i] = z4;
    for (int i=gth; i<BN; i+=gstr){ flag[i]=0u; score[i]=sc0; }
  }
  if (bid == 0){
    auto& P = SM.prep;
    if (tid == 0){
      int tl[4]; int n=0;
      for (int b=0;b<Bq;b++){
        bool eq = true;
        for (int j=1;j<NEG;j++) eq = eq && (h_index[b*NEG+j]==h_index[b*NEG]);
        int h0 = eq ? h_index[b*NEG] : t_index[b*NEG];
        int t0 = eq ? t_index[b*NEG] : h_index[b*NEG];
        int r0 = eq ? r_index[b*NEG] : r_index[b*NEG] + NUM_REL;
        P.fh[b]=h0+b*Nn; P.ft[b]=t0+b*Nn; P.r0[b]=r0;
        hdr[b]=P.fh[b]; hdr[2+b]=P.ft[b];
        for (int j=0;j<NEG;j++){
          int tj = eq ? t_index[b*NEG+j] : h_index[b*NEG+j];
          hdr[4 + b*NEG + j] = tj + b*Nn;
        }
        if (b==0){ P.hsrc=h0; P.tsrc=t0; ctr[7]=(unsigned)h0; ctr[8]=(unsigned)t0; }
        int c1 = P.ft[b]; bool f1=false;
        for (int q=0;q<n;q++) f1 = f1 || (tl[q]==c1);
        if (!f1) tl[n++] = c1;
        int c2 = P.fh[b]; bool f2=false;
        for (int q=0;q<n;q++) f2 = f2 || (tl[q]==c2);
        if (!f2) tl[n++] = c2;
      }
      for (int q=0;q<n;q++) tlist[q] = tl[q];
      ctr[3] = (unsigned)n;
      ctr[4] = __float_as_uint(sc0);
    }
    __syncthreads();
    int b = tid >> 7, d = tid & 127;
    P.relv[b][d] = rel_embedding[(size_t)P.r0[b]*Dd + d];
    if (b == 0) P.hv[d] = hidden_states[(size_t)P.hsrc*Dd + d];
    __syncthreads();
    float acc = lin_b[d];
    #pragma unroll 8
    for (int k=0;k<Dd;k++) acc += P.relv[b][k]*lin_W[(Dd+k)*Dd + d];
    P.cv[b][d] = acc; cvec[b*Dd+d] = acc;
    float heur = acc;
    #pragma unroll 8
    for (int k=0;k<Dd;k++) heur += P.hv[k]*lin_W[k*Dd + d];
    P.x[b][d] = heur * P.hv[d];
    __syncthreads();
    float a2 = m1_b[d];
    #pragma unroll 8
    for (int k=0;k<Dd;k++) a2 += P.x[b][k]*m1_W[k*Dd + d];
    P.p[b][d] = fmaxf(a2, 0.f) * m2_W[d];
    __syncthreads();
    if (tid < Bq){
      float s = m2_b[0];
      for (int k=0;k<Dd;k++) s += P.p[tid][k];
      ctr[5+tid] = __float_as_uint(s);
    }
  }
  __threadfence(); grid.sync();

  // ================= P1: boundary writes + head scores (block 0) =================
  if (bid == 0){
    if (tid < Dd){
      int hsrc=(int)ctr[7], tsrc=(int)ctr[8];
      float tv = hidden_states[(size_t)tsrc*Dd + tid];
      float hv = hidden_states[(size_t)hsrc*Dd + tid];
      hidden[(size_t)hdr[2]*Dd + tid] = tv;
      hidden[(size_t)hdr[3]*Dd + tid] = tv;
      hidden[(size_t)hdr[0]*Dd + tid] = hv;
      hidden[(size_t)hdr[1]*Dd + tid] = hv;
    }
    if (tid < Bq) score[hdr[tid]] = __uint_as_float(ctr[5+tid]);
    if (tid < (int)ctr[3]) flag[tlist[tid]] = 1u;
  }
  __threadfence(); grid.sync();

  // ================= layer loop =================
  for (int l = 0; l < Ll; ++l){
    const float* preWl  = pre_W  + (size_t)l*2*Dd*Dd;
    const float* prebl  = pre_b  + (size_t)l*Dd;
    const float* postWl = post_W + (size_t)l*12*Dd*Dd;
    const float* postbl = post_b + (size_t)l*Dd;
    const float* outWl  = out_W  + (size_t)l*Dd*Dd;
    const float* outbl  = out_b  + (size_t)l*Dd;

    // ---- A: select (blocks 0,1) + zero accumulators (blocks >=2) ----
    if (bid < 2){
      auto& S = SM.sel;
      int b = bid;
      int nt = (int)ldv(&ctr[3]);
      unsigned d0 = ~encf(__uint_as_float(ldv(&ctr[4])));
      if (tid==0){ S.ntb=0; S.pref=0ull; S.kk=K_SEL; }
      __syncthreads();
      int vlo=b*Nn, vhi=vlo+Nn;
      for (int i=tid; i<nt; i+=TPB){
        int v = tlist[i];
        if (v>=vlo && v<vhi){
          int pos = atomicAdd(&S.ntb, 1);
          if (pos < SELCAP){
            S.sd[pos] = ~encf(score[v]);
            S.sidx[pos] = (unsigned short)(v - vlo);
          }
        }
      }
      __syncthreads();
      int ntb = min(S.ntb, SELCAP);
      unsigned nvirt = (unsigned)(Nn - ntb);
      for (int pass=7; pass>=0; --pass){
        S.hist[tid]=0u; S.histT[tid]=0u;
        __syncthreads();
        unsigned long long pref = S.pref;
        int sh_hi = 8*(pass+1);
        for (int j=tid; j<ntb; j+=TPB){
          unsigned long long key = ((unsigned long long)S.sd[j] << 32) | (unsigned long long)S.sidx[j];
          bool ok = (pass==7) || ((key >> sh_hi) == (pref >> sh_hi));
          if (ok) atomicAdd(&S.hist[(unsigned)(key >> (8*pass)) & 255u], 1u);
          if (pass < 4){
            unsigned idx = S.sidx[j];
            bool oki = (pass == 3) || ((idx >> sh_hi) == (((unsigned)pref) >> sh_hi));
            if (oki) atomicAdd(&S.histT[(idx >> (8*pass)) & 255u], 1u);
          }
        }
        __syncthreads();
        if (pass >= 4){
          if (tid == 0){
            unsigned long long keyv_hi = ((unsigned long long)d0 << 32);
            bool ok = (pass==7) || ((keyv_hi >> sh_hi) == (pref >> sh_hi));
            if (ok) atomicAdd(&S.hist[(d0 >> (8*(pass-4))) & 255u], nvirt);
          }
        } else {
          if ((unsigned)(pref >> 32) == d0){
            unsigned long long hf = 0ull;
            if (pass < 3) hf = (unsigned long long)((((unsigned)pref) >> sh_hi)) << sh_hi;
            unsigned long long lo = hf + ((unsigned long long)tid << (8*pass));
            unsigned long long hi = lo + (1ull << (8*pass));
            unsigned long long nn = (unsigned long long)Nn;
            unsigned long long l2 = lo < nn ? lo : nn;
            unsigned long long h2 = hi < nn ? hi : nn;
            if (h2 > l2){
              unsigned c = (unsigned)(h2 - l2) - S.histT[tid];
              if (c > 0u) atomicAdd(&S.hist[tid], c);
            }
          }
        }
        __syncthreads();
        unsigned kk = S.kk;
        unsigned h = S.hist[tid];
        unsigned v = h;
        #pragma unroll
        for (int off=1; off<64; off<<=1){
          unsigned t = __shfl_up(v, off, 64);
          if ((tid & 63) >= off) v += t;
        }
        if ((tid & 63) == 63) S.wsum[tid>>6] = v;
        __syncthreads();
        unsigned base = 0;
        for (int w=0; w<(tid>>6); ++w) base += S.wsum[w];
        unsigned incl = v + base, excl = incl - h;
        if (h > 0u && excl < kk && kk <= incl){
          S.pref |= ((unsigned long long)tid) << (8*pass);
          S.kk = kk - excl;
        }
        __syncthreads();
      }
      if (tid==0) thr[b] = S.pref;
    } else {
      int z0 = (bid-2)*TPB + tid, zstr = (GRID-2)*TPB;
      float4 z4 = make_float4(0.f,0.f,0.f,0.f);
      uint4 zi = make_uint4(0u,0u,0u,0u);
      uint4 fi = make_uint4(~0u,~0u,~0u,~0u);
      for (int i=z0; i<MAXACT*Dd/4; i+=zstr){
        ((float4*)s1)[i]=z4; ((float4*)s2)[i]=z4;
        ((uint4*)mxb)[i]=zi; ((uint4*)mnb)[i]=fi;
      }
      for (int i=z0; i<MAXACT; i+=zstr) cnt[i]=0u;
      for (int i=z0; i<BN; i+=zstr) out_deg[i]=0u;
      if (bid==2 && tid<3) ctr[tid]=0u;
    }
    __threadfence(); grid.sync();

    // ---- B: out-degree with inline key test ----
    unsigned long long th0 = thr[0], th1 = thr[1];
    for (int e=gth; e<Ee; e+=gstr){
      int s0 = edge_index[e];
      if (make_key(score[s0], s0) <= th0) atomicAdd(&out_deg[s0], 1u);
      int v1 = s0 + Nn;
      if (make_key(score[v1], s0) <= th1) atomicAdd(&out_deg[v1], 1u);
    }
    __threadfence(); grid.sync();

    // ---- C: active-node compaction ----
    for (int v=gth; v<BN; v+=gstr){
      unsigned dg = out_deg[v];
      if (dg > 0u){
        int slot = (int)atomicAdd(&ctr[0], 1u);
        alist[slot]=v; node_slot[v]=slot; slot_deg[slot]=(float)dg;
        atomicAdd((float*)&ctr[2], logf((float)dg + 1.0f));
        if (atomicExch(&flag[v], 1u) == 0u){
          int p = (int)atomicAdd(&ctr[3], 1u);
          tlist[p] = v;
        }
      }
    }
    __threadfence(); grid.sync();

    // ---- D: build relevant-edge list ----
    for (int e=gth; e<Ee; e+=gstr){
      int s0 = edge_index[e], dn = edge_index[Ee + e];
      if (make_key(score[s0], s0) <= th0 && out_deg[dn] > 0u){
        int slot = node_slot[dn];
        int j = (int)atomicAdd(&ctr[1], 1u);
        edges[2*j] = s0; edges[2*j+1] = slot;
        atomicAdd(&cnt[slot], 1u);
      }
      int s1v = s0 + Nn, d1v = dn + Nn;
      if (make_key(score[s1v], s0) <= th1 && out_deg[d1v] > 0u){
        int slot = node_slot[d1v];
        int j = (int)atomicAdd(&ctr[1], 1u);
        edges[2*j] = s1v; edges[2*j+1] = slot;
        atomicAdd(&cnt[slot], 1u);
      }
    }
    __threadfence(); grid.sync();

    // ---- E: messages (4 edges per block-iteration) ----
    {
      auto& M = SM.msg;
      int ne = (int)ldv(&ctr[1]);
      float pb = prebl[tid & 127];
      for (int j0 = bid*4; j0 < ne; j0 += GRID*4){
        int nv = ne - j0; if (nv > 4) nv = 4;
        if (tid < 4){
          int j = j0 + ((tid < nv) ? tid : 0);
          M.dsl[tid] = edges[2*j+1];
        }
        if (tid < Dd){
          #pragma unroll
          for (int e=0;e<4;e++){
            int j = j0 + ((e < nv) ? e : 0);
            int s = edges[2*j];
            int dv = alist[edges[2*j+1]];
            M.sd[e][tid] = hidden[(size_t)dv*Dd + tid];
            M.ss[e][tid] = hidden[(size_t)s*Dd + tid];
          }
        }
        __syncthreads();
        if (tid < Dd){
          float a[4] = {pb, pb, pb, pb};
          #pragma unroll 4
          for (int k=0;k<Dd;k++){
            float w0 = preWl[k*Dd + tid];
            float w1 = preWl[(Dd+k)*Dd + tid];
            #pragma unroll
            for (int e=0;e<4;e++) a[e] += M.sd[e][k]*w0 + M.ss[e][k]*w1;
          }
          for (int e=0;e<nv;e++){
            int dslot = M.dsl[e];
            atomicAdd(&s1[dslot*Dd + tid], a[e]);
            atomicAdd(&s2[dslot*Dd + tid], a[e]*a[e]);
            atomicMax(&mxb[dslot*Dd + tid], encf(a[e]));
            atomicMin(&mnb[dslot*Dd + tid], encf(a[e]));
          }
        }
        __syncthreads();
      }
    }
    __threadfence(); grid.sync();

    // ---- F: finalize + post GEMM (64 tiles x 4 chunks x 2 col-halves) ----
    {
      auto& PP = SM.post;
      int na = (int)ldv(&ctr[0]);
      int tile = bid & 63, ch = (bid >> 6) & 3, half = bid >> 8;
      if (tile*32 < na){
        if (tid < 32){
          unsigned c = cnt[tile*32 + tid];
          PP.sden[tid] = fmaxf((float)c, 1.0f);
          PP.shas[tid] = c;
        }
        __syncthreads();
        for (int idx = tid; idx < 32*Dd; idx += TPB){
          int sl = idx >> 7, kk = idx & 127;
          int gi = (tile*32 + sl)*Dd + kk;
          float den = PP.sden[sl];
          float val;
          if (ch == 0)      val = s1[gi]/den;
          else if (ch == 1) val = PP.shas[sl] ? decf(mxb[gi]) : 0.f;
          else if (ch == 2) val = PP.shas[sl] ? decf(mnb[gi]) : 0.f;
          else {
            float mv = s1[gi]/den;
            float var = s2[gi]/den - mv*mv;
            val = sqrtf(fmaxf(var, 0.f) + EPSV);
          }
          PP.lb[sl*136 + kk] = val;
        }
        int cg = tid & 15, rg = tid >> 4;
        int c0 = cg*4;
        float a0[2][4], a1[2][4], a2[2][4];
        #pragma unroll
        for (int i=0;i<2;i++)
          #pragma unroll
          for (int j=0;j<4;j++){ a0[i][j]=0.f; a1[i][j]=0.f; a2[i][j]=0.f; }
        for (int chunk = 0; chunk < 8; ++chunk){
          __syncthreads();
          for (int f = tid; f < 768; f += TPB){
            int q = f >> 8, r = f & 255;
            int kk = r >> 4, c4 = r & 15;
            int grow = q*512 + ch*128 + chunk*16 + kk;
            ((float4*)PP.wbuf)[f] = *(const float4*)(postWl + (size_t)grow*Dd + half*64 + c4*4);
          }
          __syncthreads();
          #pragma unroll
          for (int k4 = 0; k4 < 4; ++k4){
            float4 av0 = *(const float4*)&PP.lb[(rg*2+0)*136 + chunk*16 + k4*4];
            float4 av1 = *(const float4*)&PP.lb[(rg*2+1)*136 + chunk*16 + k4*4];
            #pragma unroll
            for (int j = 0; j < 4; ++j){
              int kk = k4*4 + j;
              float4 w0 = *(const float4*)&PP.wbuf[kk*64 + c0];
              float4 w1 = *(const float4*)&PP.wbuf[1024 + kk*64 + c0];
              float4 w2 = *(const float4*)&PP.wbuf[2048 + kk*64 + c0];
              float av[2] = { (&av0.x)[j], (&av1.x)[j] };
              #pragma unroll
              for (int i=0;i<2;i++){
                float a = av[i];
                a0[i][0] += a*w0.x; a0[i][1] += a*w0.y; a0[i][2] += a*w0.z; a0[i][3] += a*w0.w;
                a1[i][0] += a*w1.x; a1[i][1] += a*w1.y; a1[i][2] += a*w1.z; a1[i][3] += a*w1.w;
                a2[i][0] += a*w2.x; a2[i][1] += a*w2.y; a2[i][2] += a*w2.z; a2[i][3] += a*w2.w;
              }
            }
          }
        }
        float logsum = __uint_as_float(ldv(&ctr[2]));
        float avg = (logsum + (float)(BN - na)*LN2F) / (float)BN;
        #pragma unroll
        for (int i=0;i<2;i++){
          int slot = tile*32 + rg*2 + i;
          if (slot < na){
            float dg = slot_deg[slot];
            float logd = logf(dg + 1.f);
            float al = logd/avg, be = avg/logd;
            float4 r;
            r.x = a0[i][0] + al*a1[i][0] + be*a2[i][0];
            r.y = a0[i][1] + al*a1[i][1] + be*a2[i][1];
            r.z = a0[i][2] + al*a1[i][2] + be*a2[i][2];
            r.w = a0[i][3] + al*a1[i][3] + be*a2[i][3];
            *(float4*)(tpart + (size_t)ch*MAXACT*Dd + (size_t)slot*Dd + half*64 + c0) = r;
          }
        }
      }
    }
    __threadfence(); grid.sync();

    // ---- G: out-linear + residual (64 tiles x 2 col-halves; blocks 0..127) ----
    if (bid < 128){
      auto& R = SM.res;
      int na = (int)ldv(&ctr[0]);
      int tile = bid & 63, half = bid >> 6;
      if (tile*32 < na){
        for (int idx = tid; idx < 32*Dd; idx += TPB){
          int sl = idx >> 7, kk = idx & 127;
          size_t o = (size_t)(tile*32 + sl)*Dd + kk;
          R.tr[sl*136 + kk] = tpart[o] + tpart[(size_t)MAXACT*Dd + o]
                            + tpart[(size_t)2*MAXACT*Dd + o] + tpart[(size_t)3*MAXACT*Dd + o]
                            + postbl[kk];
        }
        int cg = tid & 15, rg = tid >> 4;
        int c0 = cg*4;
        float4 ob = *(const float4*)(outbl + half*64 + c0);
        float acc[2][4];
        #pragma unroll
        for (int r=0;r<2;r++){ acc[r][0]=ob.x; acc[r][1]=ob.y; acc[r][2]=ob.z; acc[r][3]=ob.w; }
        for (int chunk = 0; chunk < 8; ++chunk){
          __syncthreads();
          {
            int f = tid;
            int kk = f >> 4, c4 = f & 15;
            ((float4*)R.wbuf)[f] = *(const float4*)(outWl + (size_t)(chunk*16 + kk)*Dd + half*64 + c4*4);
          }
          __syncthreads();
          #pragma unroll
          for (int k4 = 0; k4 < 4; ++k4){
            float4 av[2];
            #pragma unroll
            for (int r=0;r<2;r++)
              av[r] = *(const float4*)&R.tr[(rg*2+r)*136 + chunk*16 + k4*4];
            #pragma unroll
            for (int j = 0; j < 4; ++j){
              float4 w = *(const float4*)&R.wbuf[(k4*4+j)*64 + c0];
              #pragma unroll
              for (int r=0;r<2;r++){
                float a = (&av[r].x)[j];
                acc[r][0] += a*w.x; acc[r][1] += a*w.y; acc[r][2] += a*w.z; acc[r][3] += a*w.w;
              }
            }
          }
        }
        #pragma unroll
        for (int r=0;r<2;r++){
          int slot = tile*32 + rg*2 + r;
          if (slot < na){
            int v = alist[slot];
            float* hp = hidden + (size_t)v*Dd + half*64 + c0;
            float4 h4 = *(float4*)hp;
            h4.x += acc[r][0]; h4.y += acc[r][1]; h4.z += acc[r][2]; h4.w += acc[r][3];
            *(float4*)hp = h4;
          }
        }
      }
    }
    __threadfence(); grid.sync();

    // ---- H: score (touched list; last layer -> 32 output rows direct) ----
    {
      auto& S = SM.sco;
      const int* list; int nrow;
      if (l < Ll-1){ list = tlist; nrow = (int)ldv(&ctr[3]); }
      else         { list = hdr + 4; nrow = Bq*NEG; }
      int nb = bid * 32;
      if (nb < nrow){
        if (tid < 32){
          int idx = nb + tid;
          S.sv[tid] = (idx < nrow) ? list[idx] : list[nb];
        }
        S.sc[tid] = cvec[tid];
        __syncthreads();
        for (int q = tid; q < 32*32; q += TPB){
          int row = q >> 5, f4 = q & 31;
          ((float4*)S.sh)[row*32 + f4] = ((const float4*)(hidden + (size_t)S.sv[row]*Dd))[f4];
        }
        __syncthreads();
        int cg = tid & 31, rg = tid >> 5;
        int c0 = cg*4;
        float acc[4][4];
        #pragma unroll
        for (int i=0;i<4;i++){ acc[i][0]=0.f; acc[i][1]=0.f; acc[i][2]=0.f; acc[i][3]=0.f; }
        for (int k4=0;k4<32;k4++){
          float4 av[4];
          #pragma unroll
          for (int i=0;i<4;i++) av[i] = ((float4*)S.sh)[(rg*4+i)*32 + k4];
          #pragma unroll
          for (int j=0;j<4;j++){
            float4 w = *(const float4*)(lin_W + (size_t)(k4*4+j)*Dd + c0);
            #pragma unroll
            for (int i=0;i<4;i++){
              float a = (&av[i].x)[j];
              acc[i][0] += a*w.x; acc[i][1] += a*w.y; acc[i][2] += a*w.z; acc[i][3] += a*w.w;
            }
          }
        }
        #pragma unroll
        for (int i=0;i<4;i++){
          int row = rg*4 + i;
          int bb = (S.sv[row] >= Nn) ? 1 : 0;
          float4 cv = *(float4*)&S.sc[bb*Dd + c0];
          float4 hv = ((float4*)S.sh)[row*32 + cg];
          float4 x;
          x.x = (acc[i][0] + cv.x)*hv.x;
          x.y = (acc[i][1] + cv.y)*hv.y;
          x.z = (acc[i][2] + cv.z)*hv.z;
          x.w = (acc[i][3] + cv.w)*hv.w;
          ((float4*)S.sx)[row*32 + cg] = x;
        }
        __syncthreads();
        #pragma unroll
        for (int i=0;i<4;i++){ acc[i][0]=0.f; acc[i][1]=0.f; acc[i][2]=0.f; acc[i][3]=0.f; }
        for (int k4=0;k4<32;k4++){
          float4 av[4];
          #pragma unroll
          for (int i=0;i<4;i++) av[i] = ((float4*)S.sx)[(rg*4+i)*32 + k4];
          #pragma unroll
          for (int j=0;j<4;j++){
            float4 w = *(const float4*)(m1_W + (size_t)(k4*4+j)*Dd + c0);
            #pragma unroll
            for (int i=0;i<4;i++){
              float a = (&av[i].x)[j];
              acc[i][0] += a*w.x; acc[i][1] += a*w.y; acc[i][2] += a*w.z; acc[i][3] += a*w.w;
            }
          }
        }
        float4 mb = *(const float4*)(m1_b + c0);
        float4 mw = *(const float4*)(m2_W + c0);
        #pragma unroll
        for (int i=0;i<4;i++){
          float p0 = fmaxf(acc[i][0]+mb.x, 0.f)*mw.x;
          float p1 = fmaxf(acc[i][1]+mb.y, 0.f)*mw.y;
          float p2 = fmaxf(acc[i][2]+mb.z, 0.f)*mw.z;
          float p3 = fmaxf(acc[i][3]+mb.w, 0.f)*mw.w;
          S.red[(rg*4+i)*33 + cg] = p0+p1+p2+p3;
        }
        __syncthreads();
        if (tid < 32){
          float s = m2_b[0];
          for (int g=0; g<32; g++) s += S.red[tid*33 + g];
          if (nb + tid < nrow){
            if (l < Ll-1) score[S.sv[tid]] = s;
            else          out[nb + tid] = s;
          }
        }
      }
    }
    if (l < Ll-1){ __threadfence(); grid.sync(); }
  }
}

// ================================================================
// ============== FALLBACK: round-4 multi-kernel path =============
// ================================================================

__global__ void k_zero(float* hidden, unsigned* flag){
  int i = blockIdx.x*blockDim.x + threadIdx.x;
  if (i < BN*Dd/4) ((float4*)hidden)[i] = make_float4(0.f,0.f,0.f,0.f);
  if (i < BN) flag[i] = 0u;
}

__global__ __launch_bounds__(256) void k_prep(
    const int* h_index, const int* r_index, const int* t_index,
    const float* hidden_states, const float* rel_embedding,
    const float* lin_W, const float* lin_b, const float* m1_W, const float* m1_b,
    const float* m2_W, const float* m2_b,
    int* hdr, float* cvec, float* hidden, float* score,
    unsigned* flag, int* tlist, unsigned* ctr){
  __shared__ int sh_fh[Bq], sh_ft[Bq], sh_r0[Bq], sh_hsrc, sh_tsrc;
  __shared__ float s_relv[Bq][Dd], s_cvec[Bq][Dd], s_hv[Dd], s_x[Bq][Dd], s_p[Bq][Dd];
  __shared__ float s_s0[Dd];
  __shared__ float sc0_sh;
  int tid = threadIdx.x;
  if (tid == 0){
    int n = 0;
    for (int b=0;b<Bq;b++){
      bool eq = true;
      for (int j=1;j<NEG;j++) eq = eq && (h_index[b*NEG+j]==h_index[b*NEG]);
      int h0 = eq ? h_index[b*NEG] : t_index[b*NEG];
      int t0 = eq ? t_index[b*NEG] : h_index[b*NEG];
      int r0 = eq ? r_index[b*NEG] : r_index[b*NEG] + NUM_REL;
      sh_fh[b] = h0 + b*Nn; sh_ft[b] = t0 + b*Nn; sh_r0[b] = r0;
      hdr[0+b] = sh_fh[b]; hdr[2+b] = sh_ft[b];
      for (int j=0;j<NEG;j++){
        int tj = eq ? t_index[b*NEG+j] : h_index[b*NEG+j];
        hdr[4 + b*NEG + j] = tj + b*Nn;
      }
      if (b==0){ sh_hsrc = h0; sh_tsrc = t0; }
      if (!flag[sh_ft[b]]){ flag[sh_ft[b]] = 1u; tlist[n++] = sh_ft[b]; }
      if (!flag[sh_fh[b]]){ flag[sh_fh[b]] = 1u; tlist[n++] = sh_fh[b]; }
    }
    ctr[3] = (unsigned)n;
  }
  __syncthreads();
  int b = tid >> 7, d = tid & 127;
  s_relv[b][d] = rel_embedding[(size_t)sh_r0[b]*Dd + d];
  if (b == 0){
    s_hv[d] = hidden_states[(size_t)sh_hsrc*Dd + d];
    s_s0[d] = fmaxf(m1_b[d], 0.f) * m2_W[d];
  }
  __syncthreads();
  if (tid == 0){
    float s = m2_b[0];
    for (int k=0;k<Dd;k++) s += s_s0[k];
    sc0_sh = s;
    ctr[4] = __float_as_uint(s);
  }
  float acc = lin_b[d];
  #pragma unroll 8
  for (int k=0;k<Dd;k++) acc += s_relv[b][k]*lin_W[(Dd+k)*Dd + d];
  s_cvec[b][d] = acc; cvec[b*Dd+d] = acc;
  hidden[(size_t)sh_ft[b]*Dd + d] = hidden_states[(size_t)sh_tsrc*Dd + d];
  hidden[(size_t)sh_fh[b]*Dd + d] = hidden_states[(size_t)sh_hsrc*Dd + d];
  __syncthreads();
  float sc0 = sc0_sh;
  for (int i = tid; i < BN; i += 256) score[i] = sc0;
  float hv = s_hv[d];
  float heur = s_cvec[b][d];
  #pragma unroll 8
  for (int k=0;k<Dd;k++) heur += s_hv[k]*lin_W[k*Dd + d];
  s_x[b][d] = heur * hv;
  __syncthreads();
  float a2 = m1_b[d];
  #pragma unroll 8
  for (int k=0;k<Dd;k++) a2 += s_x[b][k]*m1_W[k*Dd + d];
  s_p[b][d] = fmaxf(a2, 0.f) * m2_W[d];
  __syncthreads();
  if (tid < Bq){
    float s = m2_b[0];
    for (int k=0;k<Dd;k++) s += s_p[tid][k];
    score[sh_fh[tid]] = s;
  }
}

__global__ __launch_bounds__(256) void k_select(
    const float* score, const int* tlist, const unsigned* ctr,
    unsigned long long* thr){
  int b = blockIdx.x;
  int nt = (int)ctr[3];
  unsigned d0 = ~encf(__uint_as_float(ctr[4]));
  __shared__ unsigned sd[SELCAP];
  __shared__ unsigned short sidx[SELCAP];
  __shared__ unsigned hist[256], histT[256];
  __shared__ int ntb_sh;
  __shared__ unsigned long long pref_sh;
  __shared__ unsigned kk_sh;
  int tid = threadIdx.x;
  if (tid==0){ ntb_sh = 0; pref_sh = 0ull; kk_sh = K_SEL; }
  __syncthreads();
  int vlo = b*Nn, vhi = vlo + Nn;
  for (int i = tid; i < nt; i += 256){
    int v = tlist[i];
    if (v >= vlo && v < vhi){
      int pos = atomicAdd(&ntb_sh, 1);
      if (pos < SELCAP){
        sd[pos] = ~encf(score[v]);
        sidx[pos] = (unsigned short)(v - vlo);
      }
    }
  }
  __syncthreads();
  int ntb = min(ntb_sh, SELCAP);
  unsigned nvirt = (unsigned)(Nn - ntb);
  for (int pass = 7; pass >= 0; --pass){
    hist[tid] = 0u; histT[tid] = 0u;
    __syncthreads();
    unsigned long long pref = pref_sh;
    int sh_hi = 8*(pass+1);
    for (int j = tid; j < ntb; j += 256){
      unsigned long long key = ((unsigned long long)sd[j] << 32) | (unsigned long long)sidx[j];
      bool ok = (pass==7) || ((key >> sh_hi) == (pref >> sh_hi));
      if (ok) atomicAdd(&hist[(unsigned)(key >> (8*pass)) & 255u], 1u);
      if (pass < 4){
        unsigned idx = sidx[j];
        bool oki = (pass == 3) || ((idx >> sh_hi) == (((unsigned)pref) >> sh_hi));
        if (oki) atomicAdd(&histT[(idx >> (8*pass)) & 255u], 1u);
      }
    }
    __syncthreads();
    if (pass >= 4){
      if (tid == 0){
        unsigned long long keyv_hi = ((unsigned long long)d0 << 32);
        bool ok = (pass==7) || ((keyv_hi >> sh_hi) == (pref >> sh_hi));
        if (ok) atomicAdd(&hist[(d0 >> (8*(pass-4))) & 255u], nvirt);
      }
    } else {
      if ((unsigned)(pref >> 32) == d0){
        unsigned long long hf = 0ull;
        if (pass < 3) hf = (unsigned long long)((((unsigned)pref) >> sh_hi)) << sh_hi;
        unsigned long long lo = hf + ((unsigned long long)tid << (8*pass));
        unsigned long long hi = lo + (1ull << (8*pass));
        unsigned long long nn = (unsigned long long)Nn;
        unsigned long long l2 = lo < nn ? lo : nn;
        unsigned long long h2 = hi < nn ? hi : nn;
        if (h2 > l2){
          unsigned c = (unsigned)(h2 - l2) - histT[tid];
          if (c > 0u) atomicAdd(&hist[tid], c);
        }
      }
    }
    __syncthreads();
    if (tid < 256){
      unsigned kk = kk_sh;
      unsigned cum = 0;
      for (int i=0;i<tid;i++) cum += hist[i];
      unsigned h = hist[tid];
      if (h > 0u && cum < kk && kk <= cum + h){
        pref_sh |= ((unsigned long long)tid) << (8*pass);
        kk_sh = kk - cum;
      }
    }
    __syncthreads();
  }
  if (tid==0) thr[b] = pref_sh;
}

__global__ void k_mask(const float* score, const unsigned long long* thr, unsigned* sel,
                       unsigned* out_deg, float* s1, float* s2,
                       unsigned* mxb, unsigned* mnb, unsigned* cnt, unsigned* ctr){
  int i = blockIdx.x*blockDim.x + threadIdx.x;
  if (i < BN){
    int b = i / Nn; int v = i - b*Nn;
    sel[i] = (make_key(score[i], v) <= thr[b]) ? 1u : 0u;
    out_deg[i] = 0u;
  }
  if (i < MAXACT*Dd){ s1[i]=0.f; s2[i]=0.f; mxb[i]=0u; mnb[i]=0xFFFFFFFFu; }
  if (i < MAXACT) cnt[i]=0u;
  if (i < 3) ctr[i]=0u;
}

__global__ void k_degree(const int* ei, const unsigned* sel, unsigned* out_deg){
  int e = blockIdx.x*blockDim.x + threadIdx.x;
  if (e >= Ee) return;
  int s0 = ei[e];
  #pragma unroll
  for (int b=0;b<Bq;b++){
    int v = s0 + b*Nn;
    if (sel[v]) atomicAdd(&out_deg[v], 1u);
  }
}

__global__ void k_active(const unsigned* out_deg, int* node_slot, int* alist,
                         float* slot_deg, unsigned* ctr, unsigned* flag, int* tlist){
  int v = blockIdx.x*blockDim.x + threadIdx.x;
  if (v >= BN) return;
  unsigned dg = out_deg[v];
  if (dg > 0u){
    int slot = (int)atomicAdd(&ctr[0], 1u);
    alist[slot] = v; node_slot[v] = slot; slot_deg[slot] = (float)dg;
    atomicAdd((float*)&ctr[2], logf((float)dg + 1.0f));
    if (atomicExch(&flag[v], 1u) == 0u){
      int p = (int)atomicAdd(&ctr[3], 1u);
      tlist[p] = v;
    }
  }
}

__global__ void k_edges(const int* ei, const unsigned* sel, const unsigned* out_deg,
                        const int* node_slot, int* edges, unsigned* cnt, unsigned* ctr){
  int e = blockIdx.x*blockDim.x + threadIdx.x;
  if (e >= Ee) return;
  int s0 = ei[e], d0 = ei[Ee + e];
  #pragma unroll
  for (int b=0;b<Bq;b++){
    int s = s0 + b*Nn, dv = d0 + b*Nn;
    if (sel[s] && out_deg[dv] > 0u){
      int slot = node_slot[dv];
      int j = (int)atomicAdd(&ctr[1], 1u);
      edges[2*j] = s; edges[2*j+1] = slot;
      atomicAdd(&cnt[slot], 1u);
    }
  }
}

__global__ __launch_bounds__(128) void k_messages(
    const float* hidden, const int* edges, const int* alist,
    const float* preW, const float* preb,
    float* s1, float* s2, unsigned* mxb, unsigned* mnb, const unsigned* ctr){
  int ne = (int)ctr[1];
  int tid = threadIdx.x;
  __shared__ float sd[4][Dd], ss[4][Dd];
  __shared__ int dsl[4];
  float pb = preb[tid];
  for (int j0 = blockIdx.x*4; j0 < ne; j0 += gridDim.x*4){
    int nv = ne - j0; if (nv > 4) nv = 4;
    if (tid < 4){
      int j = j0 + ((tid < nv) ? tid : 0);
      dsl[tid] = edges[2*j+1];
    }
    #pragma unroll
    for (int e=0;e<4;e++){
      int j = j0 + ((e < nv) ? e : 0);
      int s = edges[2*j];
      int dv = alist[edges[2*j+1]];
      sd[e][tid] = hidden[(size_t)dv*Dd + tid];
      ss[e][tid] = hidden[(size_t)s*Dd + tid];
    }
    __syncthreads();
    float a[4] = {pb, pb, pb, pb};
    #pragma unroll 4
    for (int k=0;k<Dd;k++){
      float w0 = preW[k*Dd + tid];
      float w1 = preW[(Dd+k)*Dd + tid];
      #pragma unroll
      for (int e=0;e<4;e++) a[e] += sd[e][k]*w0 + ss[e][k]*w1;
    }
    for (int e=0;e<nv;e++){
      int dslot = dsl[e];
      atomicAdd(&s1[dslot*Dd + tid], a[e]);
      atomicAdd(&s2[dslot*Dd + tid], a[e]*a[e]);
      atomicMax(&mxb[dslot*Dd + tid], encf(a[e]));
      atomicMin(&mnb[dslot*Dd + tid], encf(a[e]));
    }
    __syncthreads();
  }
}

__global__ __launch_bounds__(512) void k_post(
    const unsigned* cnt, const float* s1, const float* s2,
    const unsigned* mxb, const unsigned* mnb, const float* slot_deg,
    const float* postW, float* tpart, const unsigned* ctr){
  int na = (int)ctr[0];
  int bid = blockIdx.x;
  int tile = bid & 63, ch = bid >> 6;
  if (tile*32 >= na) return;
  float logsum = __uint_as_float(ctr[2]);
  float avg = (logsum + (float)(BN - na)*LN2F) / (float)BN;
  __shared__ float lb[32*136];
  __shared__ float wbuf[3*16*128];
  __shared__ float sden[32];
  __shared__ unsigned shas[32];
  int tid = threadIdx.x;
  if (tid < 32){
    unsigned c = cnt[tile*32 + tid];
    sden[tid] = fmaxf((float)c, 1.0f);
    shas[tid] = c;
  }
  __syncthreads();
  for (int idx = tid; idx < 32*Dd; idx += 512){
    int sl = idx >> 7, kk = idx & 127;
    int gi = (tile*32 + sl)*Dd + kk;
    float den = sden[sl];
    float val;
    if (ch == 0)      val = s1[gi]/den;
    else if (ch == 1) val = shas[sl] ? decf(mxb[gi]) : 0.f;
    else if (ch == 2) val = shas[sl] ? decf(mnb[gi]) : 0.f;
    else {
      float mv = s1[gi]/den;
      float var = s2[gi]/den - mv*mv;
      val = sqrtf(fmaxf(var, 0.f) + EPSV);
    }
    lb[sl*136 + kk] = val;
  }
  int cg = tid & 31, rg = tid >> 5;
  int c0 = cg*4;
  float a0[2][4], a1[2][4], a2[2][4];
  #pragma unroll
  for (int i=0;i<2;i++)
    #pragma unroll
    for (int j=0;j<4;j++){ a0[i][j]=0.f; a1[i][j]=0.f; a2[i][j]=0.f; }
  for (int chunk = 0; chunk < 8; ++chunk){
    #pragma unroll
    for (int i = 0; i < 3; ++i){
      int f = tid + i*512;
      int q = f >> 9, r = f & 511;
      int kk = r >> 5, c4 = r & 31;
      int grow = q*512 + ch*128 + chunk*16 + kk;
      ((float4*)wbuf)[f] = *(const float4*)(postW + (size_t)grow*Dd + c4*4);
    }
    __syncthreads();
    #pragma unroll
    for (int k4 = 0; k4 < 4; ++k4){
      float4 av0 = *(const float4*)&lb[(rg*2+0)*136 + chunk*16 + k4*4];
      float4 av1 = *(const float4*)&lb[(rg*2+1)*136 + chunk*16 + k4*4];
      #pragma unroll
      for (int j = 0; j < 4; ++j){
        int kk = k4*4 + j;
        float4 w0 = *(const float4*)&wbuf[kk*128 + c0];
        float4 w1 = *(const float4*)&wbuf[(16+kk)*128 + c0];
        float4 w2 = *(const float4*)&wbuf[(32+kk)*128 + c0];
        float av[2] = { (&av0.x)[j], (&av1.x)[j] };
        #pragma unroll
        for (int i=0;i<2;i++){
          float a = av[i];
          a0[i][0] += a*w0.x; a0[i][1] += a*w0.y; a0[i][2] += a*w0.z; a0[i][3] += a*w0.w;
          a1[i][0] += a*w1.x; a1[i][1] += a*w1.y; a1[i][2] += a*w1.z; a1[i][3] += a*w1.w;
          a2[i][0] += a*w2.x; a2[i][1] += a*w2.y; a2[i][2] += a*w2.z; a2[i][3] += a*w2.w;
        }
      }
    }
    __syncthreads();
  }
  #pragma unroll
  for (int i=0;i<2;i++){
    int slot = tile*32 + rg*2 + i;
    if (slot < na){
      float dg = slot_deg[slot];
      float logd = logf(dg + 1.f);
      float al = logd/avg, be = avg/logd;
      float4 r;
      r.x = a0[i][0] + al*a1[i][0] + be*a2[i][0];
      r.y = a0[i][1] + al*a1[i][1] + be*a2[i][1];
      r.z = a0[i][2] + al*a1[i][2] + be*a2[i][2];
      r.w = a0[i][3] + al*a1[i][3] + be*a2[i][3];
      *(float4*)(tpart + (size_t)ch*MAXACT*Dd + (size_t)slot*Dd + c0) = r;
    }
  }
}

__global__ __launch_bounds__(256) void k_out_resid(
    const float* tpart, const int* alist, const float* outW, const float* outb,
    const float* postb, float* hidden, const unsigned* ctr){
  int na = (int)ctr[0];
  int tile = blockIdx.x;
  if (tile*32 >= na) return;
  __shared__ float tr[32*136];
  __shared__ float wbuf[16*128];
  int tid = threadIdx.x;
  for (int idx = tid; idx < 32*Dd; idx += 256){
    int sl = idx >> 7, kk = idx & 127;
    size_t o = (size_t)(tile*32 + sl)*Dd + kk;
    tr[sl*136 + kk] = tpart[o] + tpart[(size_t)MAXACT*Dd + o]
                    + tpart[(size_t)2*MAXACT*Dd + o] + tpart[(size_t)3*MAXACT*Dd + o]
                    + postb[kk];
  }
  int cg = tid & 31, rg = tid >> 5;
  int c0 = cg*4;
  float4 ob = *(const float4*)(outb + c0);
  float acc[4][4];
  #pragma unroll
  for (int r=0;r<4;r++){ acc[r][0]=ob.x; acc[r][1]=ob.y; acc[r][2]=ob.z; acc[r][3]=ob.w; }
  for (int chunk = 0; chunk < 8; ++chunk){
    #pragma unroll
    for (int i = 0; i < 2; ++i){
      int f = tid + i*256;
      int kk = f >> 5, c4 = f & 31;
      ((float4*)wbuf)[f] = *(const float4*)(outW + (size_t)(chunk*16 + kk)*Dd + c4*4);
    }
    __syncthreads();
    #pragma unroll
    for (int k4 = 0; k4 < 4; ++k4){
      float4 av[4];
      #pragma unroll
      for (int r=0;r<4;r++)
        av[r] = *(const float4*)&tr[(rg*4+r)*136 + chunk*16 + k4*4];
      #pragma unroll
      for (int j = 0; j < 4; ++j){
        float4 w = *(const float4*)&wbuf[(k4*4+j)*128 + c0];
        #pragma unroll
        for (int r=0;r<4;r++){
          float a = (&av[r].x)[j];
          acc[r][0] += a*w.x; acc[r][1] += a*w.y; acc[r][2] += a*w.z; acc[r][3] += a*w.w;
        }
      }
    }
    __syncthreads();
  }
  #pragma unroll
  for (int r=0;r<4;r++){
    int slot = tile*32 + rg*4 + r;
    if (slot < na){
      int v = alist[slot];
      float* hp = hidden + (size_t)v*Dd + c0;
      float4 h4 = *(float4*)hp;
      h4.x += acc[r][0]; h4.y += acc[r][1]; h4.z += acc[r][2]; h4.w += acc[r][3];
      *(float4*)hp = h4;
    }
  }
}

__global__ __launch_bounds__(256) void k_score(
    const float* hidden, const float* cvec, const float* linW,
    const float* m1W, const float* m1b, const float* m2W, const float* m2b,
    const int* tlist, const unsigned* ctr, float* score,
    const int* ovr, int ovr_n){
  int nt = (ovr_n > 0) ? ovr_n : (int)ctr[3];
  const int* list = (ovr_n > 0) ? ovr : tlist;
  int nb = blockIdx.x * 32;
  if (nb >= nt) return;
  __shared__ float sh[32*Dd];
  __shared__ float sx[32*Dd];
  __shared__ float sc[2*Dd];
  __shared__ int   sv[32];
  __shared__ float red[32*33];
  int tid = threadIdx.x;
  if (tid < 32){
    int idx = nb + tid;
    sv[tid] = (idx < nt) ? list[idx] : list[nb];
  }
  sc[tid] = cvec[tid];
  __syncthreads();
  for (int q = tid; q < 32*32; q += 256){
    int row = q >> 5, f4 = q & 31;
    ((float4*)sh)[row*32 + f4] = ((const float4*)(hidden + (size_t)sv[row]*Dd))[f4];
  }
  __syncthreads();
  int cg = tid & 31, rg = tid >> 5;
  int c0 = cg*4;
  float acc[4][4];
  #pragma unroll
  for (int i=0;i<4;i++){ acc[i][0]=0.f; acc[i][1]=0.f; acc[i][2]=0.f; acc[i][3]=0.f; }
  for (int k4=0;k4<32;k4++){
    float4 av[4];
    #pragma unroll
    for (int i=0;i<4;i++) av[i] = ((float4*)sh)[(rg*4+i)*32 + k4];
    #pragma unroll
    for (int j=0;j<4;j++){
      float4 w = *(const float4*)(linW + (size_t)(k4*4+j)*Dd + c0);
      #pragma unroll
      for (int i=0;i<4;i++){
        float a = (&av[i].x)[j];
        acc[i][0] += a*w.x; acc[i][1] += a*w.y; acc[i][2] += a*w.z; acc[i][3] += a*w.w;
      }
    }
  }
  #pragma unroll
  for (int i=0;i<4;i++){
    int row = rg*4 + i;
    int bb = (sv[row] >= Nn) ? 1 : 0;
    float4 cv = *(float4*)&sc[bb*Dd + c0];
    float4 hv = ((float4*)sh)[row*32 + cg];
    float4 x;
    x.x = (acc[i][0] + cv.x)*hv.x;
    x.y = (acc[i][1] + cv.y)*hv.y;
    x.z = (acc[i][2] + cv.z)*hv.z;
    x.w = (acc[i][3] + cv.w)*hv.w;
    ((float4*)sx)[row*32 + cg] = x;
  }
  __syncthreads();
  #pragma unroll
  for (int i=0;i<4;i++){ acc[i][0]=0.f; acc[i][1]=0.f; acc[i][2]=0.f; acc[i][3]=0.f; }
  for (int k4=0;k4<32;k4++){
    float4 av[4];
    #pragma unroll
    for (int i=0;i<4;i++) av[i] = ((float4*)sx)[(rg*4+i)*32 + k4];
    #pragma unroll
    for (int j=0;j<4;j++){
      float4 w = *(const float4*)(m1W + (size_t)(k4*4+j)*Dd + c0);
      #pragma unroll
      for (int i=0;i<4;i++){
        float a = (&av[i].x)[j];
        acc[i][0] += a*w.x; acc[i][1] += a*w.y; acc[i][2] += a*w.z; acc[i][3] += a*w.w;
      }
    }
  }
  float4 mb = *(const float4*)(m1b + c0);
  float4 mw = *(const float4*)(m2W + c0);
  #pragma unroll
  for (int i=0;i<4;i++){
    float p0 = fmaxf(acc[i][0]+mb.x, 0.f)*mw.x;
    float p1 = fmaxf(acc[i][1]+mb.y, 0.f)*mw.y;
    float p2 = fmaxf(acc[i][2]+mb.z, 0.f)*mw.z;
    float p3 = fmaxf(acc[i][3]+mb.w, 0.f)*mw.w;
    red[(rg*4+i)*33 + cg] = p0+p1+p2+p3;
  }
  __syncthreads();
  if (tid < 32){
    float s = m2b[0];
    for (int g=0; g<32; g++) s += red[tid*33 + g];
    if (nb + tid < nt) score[sv[tid]] = s;
  }
}

__global__ void k_gather(const float* score, const int* hdr, float* out){
  int i = threadIdx.x;
  if (i < Bq*NEG) out[i] = score[hdr[4+i]];
}

// ---------------- launch ----------------
extern "C" void kernel_launch(void* const* d_in, const int* in_sizes, int n_in,
                              void* d_out, int out_size, void* d_ws, size_t ws_size,
                              hipStream_t stream){
  const int*   h_index       = (const int*)d_in[0];
  const int*   r_index       = (const int*)d_in[1];
  const int*   t_index       = (const int*)d_in[2];
  const float* hidden_states = (const float*)d_in[3];
  const int*   edge_index    = (const int*)d_in[4];
  const float* rel_embedding = (const float*)d_in[5];
  const float* lin_W  = (const float*)d_in[6];
  const float* lin_b  = (const float*)d_in[7];
  const float* m1_W   = (const float*)d_in[8];
  const float* m1_b   = (const float*)d_in[9];
  const float* m2_W   = (const float*)d_in[10];
  const float* m2_b   = (const float*)d_in[11];
  const float* pre_W  = (const float*)d_in[12];
  const float* pre_b  = (const float*)d_in[13];
  const float* post_W = (const float*)d_in[14];
  const float* post_b = (const float*)d_in[15];
  const float* out_W  = (const float*)d_in[16];
  const float* out_b  = (const float*)d_in[17];
  char*  wsp  = (char*)d_ws;
  float* outp = (float*)d_out;

  void* kargs[] = {
    (void*)&h_index, (void*)&r_index, (void*)&t_index, (void*)&hidden_states,
    (void*)&edge_index, (void*)&rel_embedding, (void*)&lin_W, (void*)&lin_b,
    (void*)&m1_W, (void*)&m1_b, (void*)&m2_W, (void*)&m2_b,
    (void*)&pre_W, (void*)&pre_b, (void*)&post_W, (void*)&post_b,
    (void*)&out_W, (void*)&out_b, (void*)&wsp, (void*)&outp
  };
  hipError_t err = hipLaunchCooperativeKernel((void*)fused, dim3(GRID), dim3(TPB),
                                              kargs, 0, stream);
  if (err == hipSuccess) return;

  // -------- fallback: round-4 multi-kernel path (identical numerics) --------
  float*    hidden   = (float*)(wsp + HID_OFF);
  float*    score    = (float*)(wsp + SCORE_OFF);
  float*    cvec     = (float*)(wsp + CVEC_OFF);
  int*      hdr      = (int*)(wsp + HDR_OFF);
  unsigned long long* thr = (unsigned long long*)(wsp + THR_OFF);
  unsigned* sel      = (unsigned*)(wsp + SEL_OFF);
  unsigned* out_deg  = (unsigned*)(wsp + DEG_OFF);
  int*      node_slot= (int*)(wsp + SLOT_OFF);
  unsigned* cnt      = (unsigned*)(wsp + CNT_OFF);
  float*    slot_deg = (float*)(wsp + SDEG_OFF);
  float*    s1       = (float*)(wsp + S1_OFF);
  float*    s2       = (float*)(wsp + S2_OFF);
  unsigned* mxb      = (unsigned*)(wsp + MXB_OFF);
  unsigned* mnb      = (unsigned*)(wsp + MNB_OFF);
  float*    tpart    = (float*)(wsp + TPART_OFF);
  int*      alist    = (int*)(wsp + ALIST_OFF);
  unsigned* flag     = (unsigned*)(wsp + FLAG_OFF);
  int*      tlist    = (int*)(wsp + TLIST_OFF);
  int*      edges    = (int*)(wsp + EDGE_OFF);
  unsigned* ctr      = (unsigned*)(wsp + CTR_OFF);

  k_zero<<<(BN*Dd/4 + 255)/256, 256, 0, stream>>>(hidden, flag);
  k_prep<<<1, 256, 0, stream>>>(h_index, r_index, t_index, hidden_states, rel_embedding,
                                lin_W, lin_b, m1_W, m1_b, m2_W, m2_b,
                                hdr, cvec, hidden, score, flag, tlist, ctr);
  for (int l = 0; l < Ll; ++l){
    const float* preWl  = pre_W  + (size_t)l*2*Dd*Dd;
    const float* prebl  = pre_b  + (size_t)l*Dd;
    const float* postWl = post_W + (size_t)l*12*Dd*Dd;
    const float* postbl = post_b + (size_t)l*Dd;
    const float* outWl  = out_W  + (size_t)l*Dd*Dd;
    const float* outbl  = out_b  + (size_t)l*Dd;

    k_select<<<Bq, 256, 0, stream>>>(score, tlist, ctr, thr);
    k_mask<<<(MAXACT*Dd + 255)/256, 256, 0, stream>>>(score, thr, sel, out_deg,
                                                      s1, s2, mxb, mnb, cnt, ctr);
    k_degree<<<(Ee + 255)/256, 256, 0, stream>>>(edge_index, sel, out_deg);
    k_active<<<(BN + 255)/256, 256, 0, stream>>>(out_deg, node_slot, alist, slot_deg,
                                                 ctr, flag, tlist);
    k_edges<<<(Ee + 255)/256, 256, 0, stream>>>(edge_index, sel, out_deg, node_slot,
                                                edges, cnt, ctr);
    k_messages<<<512, 128, 0, stream>>>(hidden, edges, alist, preWl, prebl,
                                        s1, s2, mxb, mnb, ctr);
    k_post<<<256, 512, 0, stream>>>(cnt, s1, s2, mxb, mnb, slot_deg, postWl, tpart, ctr);
    k_out_resid<<<MAXACT/32, 256, 0, stream>>>(tpart, alist, outWl, outbl, postbl,
                                               hidden, ctr);
    if (l < Ll-1){
      k_score<<<MAXTOUCH/32, 256, 0, stream>>>(hidden, cvec, lin_W, m1_W, m1_b, m2_W, m2_b,
                                               tlist, ctr, score, tlist, 0);
    } else {
      k_score<<<1, 256, 0, stream>>>(hidden, cvec, lin_W, m1_W, m1_b, m2_W, m2_b,
                                     tlist, ctr, score, hdr + 4, Bq*NEG);
    }
  }
  k_gather<<<1, 64, 0, stream>>>(score, hdr, outp);
}

// Round 7
// 538.613 us; speedup vs baseline: 5.9538x; 5.9538x over previous
//
#include <hip/hip_runtime.h>
#include <math.h>

#define Bq 2
#define NEG 16
#define Nn 10000
#define Ee 80000
#define Dd 128
#define NUM_REL 237
#define Ll 3
#define K_SEL 1000
#define BN (Bq*Nn)
#define EPSV 1e-5f
#define MAXACT 2048
#define MAXTOUCH 8192
#define SELCAP 3328
#define LN2F 0.69314718056f

// ---------------- workspace layout (bytes) ----------------
constexpr size_t HID_OFF   = 0;                                   // BN*D f32
constexpr size_t SCORE_OFF = HID_OFF   + (size_t)BN*Dd*4;         // BN f32
constexpr size_t CVEC_OFF  = SCORE_OFF + (size_t)BN*4;            // B*D f32
constexpr size_t HDR_OFF   = CVEC_OFF  + (size_t)Bq*Dd*4;         // 64 i32
constexpr size_t THR_OFF   = HDR_OFF   + 64*4;                    // B u64
constexpr size_t DEG_OFF   = THR_OFF   + 64*8;                    // BN u32
constexpr size_t SLOT_OFF  = DEG_OFF   + (size_t)BN*4;            // BN i32
constexpr size_t CNT_OFF   = SLOT_OFF  + (size_t)BN*4;            // MAXACT u32
constexpr size_t SDEG_OFF  = CNT_OFF   + (size_t)MAXACT*4;        // MAXACT f32
constexpr size_t S1_OFF    = SDEG_OFF  + (size_t)MAXACT*4;        // MAXACT*D f32
constexpr size_t S2_OFF    = S1_OFF    + (size_t)MAXACT*Dd*4;
constexpr size_t MXB_OFF   = S2_OFF    + (size_t)MAXACT*Dd*4;     // MAXACT*D u32
constexpr size_t MNB_OFF   = MXB_OFF   + (size_t)MAXACT*Dd*4;
constexpr size_t TPART_OFF = MNB_OFF   + (size_t)MAXACT*Dd*4;     // 4*MAXACT*D f32
constexpr size_t ALIST_OFF = TPART_OFF + (size_t)4*MAXACT*Dd*4;   // MAXACT i32
constexpr size_t FLAG_OFF  = ALIST_OFF + (size_t)MAXACT*4;        // BN u32
constexpr size_t TLIST_OFF = FLAG_OFF  + (size_t)BN*4;            // MAXTOUCH i32
constexpr size_t EDGE_OFF  = TLIST_OFF + (size_t)MAXTOUCH*4;      // 2*B*E i32 (sedges)
constexpr size_t CTR_OFF   = EDGE_OFF  + (size_t)Bq*Ee*2*4;       // 16 u32
// ctr[0]=na ctr[1]=ns(selected-src edges) ctr[2]=log-sum f32bits ctr[3]=ntouched ctr[4]=sc0 bits

// ---------------- helpers ----------------
__device__ __forceinline__ unsigned encf(float f){
  unsigned u = __float_as_uint(f);
  return (u & 0x80000000u) ? ~u : (u | 0x80000000u);
}
__device__ __forceinline__ float decf(unsigned e){
  unsigned u = (e & 0x80000000u) ? (e & 0x7FFFFFFFu) : ~e;
  return __uint_as_float(u);
}
__device__ __forceinline__ unsigned long long make_key(float f, int i){
  unsigned d = ~encf(f);
  return ((unsigned long long)d << 32) | (unsigned)i;
}

// ---------------- k_init: zero+fill+boundary+prep in one dispatch ----------------
__global__ __launch_bounds__(256) void k_init(
    const int* h_index, const int* r_index, const int* t_index,
    const float* hidden_states, const float* rel_embedding,
    const float* lin_W, const float* lin_b, const float* m1_W, const float* m1_b,
    const float* m2_W, const float* m2_b,
    int* hdr, float* cvec, float* hidden, float* score,
    unsigned* flag, int* tlist, unsigned* ctr){
  __shared__ int sfh[Bq], sft[Bq], sr0[Bq], shsrc, stsrc;
  __shared__ float sp[Dd];
  __shared__ float ssc0;
  __shared__ float relv[Bq][Dd], cvv[Bq][Dd], hv[Dd], xx[Bq][Dd], pp[Bq][Dd];
  int tid = threadIdx.x;
  if (tid == 0){
    for (int b=0;b<Bq;b++){
      bool eq = true;
      for (int j=1;j<NEG;j++) eq = eq && (h_index[b*NEG+j]==h_index[b*NEG]);
      int h0 = eq ? h_index[b*NEG] : t_index[b*NEG];
      int t0 = eq ? t_index[b*NEG] : h_index[b*NEG];
      int r0 = eq ? r_index[b*NEG] : r_index[b*NEG] + NUM_REL;
      sfh[b] = h0 + b*Nn; sft[b] = t0 + b*Nn; sr0[b] = r0;
      if (b==0){ shsrc = h0; stsrc = t0; }
    }
  }
  if (tid < Dd) sp[tid] = fmaxf(m1_b[tid], 0.f) * m2_W[tid];
  __syncthreads();
  if (tid == 0){
    float s = m2_b[0];
    for (int k=0;k<Dd;k++) s += sp[k];    // serial order == round-4 sc0
    ssc0 = s;
  }
  __syncthreads();
  float sc0 = ssc0;
  int fh0 = sfh[0], fh1 = sfh[1], ft0 = sft[0], ft1 = sft[1];
  int gth = blockIdx.x*256 + tid, gstr = gridDim.x*256;
  // hidden rows: zero, boundary rows get h/t values directly (h priority on collision)
  for (int i = gth; i < BN*Dd/4; i += gstr){
    int row = i >> 5, c4 = i & 31;
    float4 v;
    if (row == fh0 || row == fh1)
      v = ((const float4*)(hidden_states + (size_t)shsrc*Dd))[c4];
    else if (row == ft0 || row == ft1)
      v = ((const float4*)(hidden_states + (size_t)stsrc*Dd))[c4];
    else v = make_float4(0.f,0.f,0.f,0.f);
    ((float4*)hidden)[i] = v;
  }
  for (int i = gth; i < BN; i += gstr){
    flag[i] = (i==fh0 || i==fh1 || i==ft0 || i==ft1) ? 1u : 0u;
    if (i != fh0 && i != fh1) score[i] = sc0;   // head rows written by block 0 below
  }
  if (blockIdx.x == 0){
    if (tid == 0){
      int tl[4]; int n = 0;
      for (int b=0;b<Bq;b++){
        hdr[b] = sfh[b]; hdr[2+b] = sft[b];
        bool eq = true;
        for (int j=1;j<NEG;j++) eq = eq && (h_index[b*NEG+j]==h_index[b*NEG]);
        for (int j=0;j<NEG;j++){
          int tj = eq ? t_index[b*NEG+j] : h_index[b*NEG+j];
          hdr[4 + b*NEG + j] = tj + b*Nn;
        }
        int c1 = sft[b]; bool f1=false;
        for (int q=0;q<n;q++) f1 = f1 || (tl[q]==c1);
        if (!f1) tl[n++] = c1;
        int c2 = sfh[b]; bool f2=false;
        for (int q=0;q<n;q++) f2 = f2 || (tl[q]==c2);
        if (!f2) tl[n++] = c2;
      }
      for (int q=0;q<n;q++) tlist[q] = tl[q];
      ctr[3] = (unsigned)n;
      ctr[4] = __float_as_uint(sc0);
    }
    int b = tid >> 7, d = tid & 127;
    relv[b][d] = rel_embedding[(size_t)sr0[b]*Dd + d];
    if (b == 0) hv[d] = hidden_states[(size_t)shsrc*Dd + d];
    __syncthreads();
    float acc = lin_b[d];
    #pragma unroll 8
    for (int k=0;k<Dd;k++) acc += relv[b][k]*lin_W[(Dd+k)*Dd + d];
    cvv[b][d] = acc; cvec[b*Dd+d] = acc;
    float heur = acc;
    #pragma unroll 8
    for (int k=0;k<Dd;k++) heur += hv[k]*lin_W[k*Dd + d];
    xx[b][d] = heur * hv[d];
    __syncthreads();
    float a2 = m1_b[d];
    #pragma unroll 8
    for (int k=0;k<Dd;k++) a2 += xx[b][k]*m1_W[k*Dd + d];
    pp[b][d] = fmaxf(a2, 0.f) * m2_W[d];
    __syncthreads();
    if (tid < Bq){
      float s = m2_b[0];
      for (int k=0;k<Dd;k++) s += pp[tid][k];
      score[sfh[tid]] = s;
    }
  }
}

// ---------------- k_selz: blocks 0,1 radix-select; blocks 2+ zero accumulators ----------------
__global__ __launch_bounds__(256) void k_selz(
    const float* score, const int* tlist, unsigned* ctr, unsigned long long* thr,
    unsigned* out_deg, float* s1, float* s2, unsigned* mxb, unsigned* mnb, unsigned* cnt){
  int bid = blockIdx.x, tid = threadIdx.x;
  if (bid >= 2){
    int z0 = (bid-2)*256 + tid, zstr = (gridDim.x-2)*256;
    float4 z4 = make_float4(0.f,0.f,0.f,0.f);
    uint4 zi = make_uint4(0u,0u,0u,0u);
    uint4 fi = make_uint4(~0u,~0u,~0u,~0u);
    for (int i=z0; i<MAXACT*Dd/4; i+=zstr){
      ((float4*)s1)[i]=z4; ((float4*)s2)[i]=z4;
      ((uint4*)mxb)[i]=zi; ((uint4*)mnb)[i]=fi;
    }
    for (int i=z0; i<BN; i+=zstr) out_deg[i]=0u;
    for (int i=z0; i<MAXACT; i+=zstr) cnt[i]=0u;
    if (bid==2 && tid<3) ctr[tid]=0u;
    return;
  }
  int b = bid;
  int nt = (int)ctr[3];
  unsigned d0 = ~encf(__uint_as_float(ctr[4]));
  __shared__ unsigned sd[SELCAP];
  __shared__ unsigned short sidx[SELCAP];
  __shared__ unsigned hist[256], histT[256];
  __shared__ int ntb_sh;
  __shared__ unsigned long long pref_sh;
  __shared__ unsigned kk_sh;
  if (tid==0){ ntb_sh = 0; pref_sh = 0ull; kk_sh = K_SEL; }
  __syncthreads();
  int vlo = b*Nn, vhi = vlo + Nn;
  for (int i = tid; i < nt; i += 256){
    int v = tlist[i];
    if (v >= vlo && v < vhi){
      int pos = atomicAdd(&ntb_sh, 1);
      if (pos < SELCAP){
        sd[pos] = ~encf(score[v]);
        sidx[pos] = (unsigned short)(v - vlo);
      }
    }
  }
  __syncthreads();
  int ntb = min(ntb_sh, SELCAP);
  unsigned nvirt = (unsigned)(Nn - ntb);
  for (int pass = 7; pass >= 0; --pass){
    hist[tid] = 0u; histT[tid] = 0u;
    __syncthreads();
    unsigned long long pref = pref_sh;
    int sh_hi = 8*(pass+1);
    for (int j = tid; j < ntb; j += 256){
      unsigned long long key = ((unsigned long long)sd[j] << 32) | (unsigned long long)sidx[j];
      bool ok = (pass==7) || ((key >> sh_hi) == (pref >> sh_hi));
      if (ok) atomicAdd(&hist[(unsigned)(key >> (8*pass)) & 255u], 1u);
      if (pass < 4){
        unsigned idx = sidx[j];
        bool oki = (pass == 3) || ((idx >> sh_hi) == (((unsigned)pref) >> sh_hi));
        if (oki) atomicAdd(&histT[(idx >> (8*pass)) & 255u], 1u);
      }
    }
    __syncthreads();
    if (pass >= 4){
      if (tid == 0){
        unsigned long long keyv_hi = ((unsigned long long)d0 << 32);
        bool ok = (pass==7) || ((keyv_hi >> sh_hi) == (pref >> sh_hi));
        if (ok) atomicAdd(&hist[(d0 >> (8*(pass-4))) & 255u], nvirt);
      }
    } else {
      if ((unsigned)(pref >> 32) == d0){
        unsigned long long hf = 0ull;
        if (pass < 3) hf = (unsigned long long)((((unsigned)pref) >> sh_hi)) << sh_hi;
        unsigned long long lo = hf + ((unsigned long long)tid << (8*pass));
        unsigned long long hi = lo + (1ull << (8*pass));
        unsigned long long nn = (unsigned long long)Nn;
        unsigned long long l2 = lo < nn ? lo : nn;
        unsigned long long h2 = hi < nn ? hi : nn;
        if (h2 > l2){
          unsigned c = (unsigned)(h2 - l2) - histT[tid];
          if (c > 0u) atomicAdd(&hist[tid], c);
        }
      }
    }
    __syncthreads();
    if (tid < 256){
      unsigned kk = kk_sh;
      unsigned cum = 0;
      for (int i=0;i<tid;i++) cum += hist[i];
      unsigned h = hist[tid];
      if (h > 0u && cum < kk && kk <= cum + h){
        pref_sh |= ((unsigned long long)tid) << (8*pass);
        kk_sh = kk - cum;
      }
    }
    __syncthreads();
  }
  if (tid==0) thr[b] = pref_sh;
}

// ---------------- k_degree: inline key test + append selected-src edges ----------------
__global__ void k_degree(const int* ei, const float* score, const unsigned long long* thr,
                         unsigned* out_deg, int* sedges, unsigned* ctr){
  int e = blockIdx.x*blockDim.x + threadIdx.x;
  if (e >= Ee) return;
  unsigned long long th0 = thr[0], th1 = thr[1];
  int s0 = ei[e], d0 = ei[Ee + e];
  if (make_key(score[s0], s0) <= th0){
    atomicAdd(&out_deg[s0], 1u);
    int j = (int)atomicAdd(&ctr[1], 1u);
    sedges[2*j] = s0; sedges[2*j+1] = d0;
  }
  int s1v = s0 + Nn, d1v = d0 + Nn;
  if (make_key(score[s1v], s0) <= th1){
    atomicAdd(&out_deg[s1v], 1u);
    int j = (int)atomicAdd(&ctr[1], 1u);
    sedges[2*j] = s1v; sedges[2*j+1] = d1v;
  }
}

__global__ void k_active(const unsigned* out_deg, int* node_slot, int* alist,
                         float* slot_deg, unsigned* ctr, unsigned* flag, int* tlist){
  int v = blockIdx.x*blockDim.x + threadIdx.x;
  if (v >= BN) return;
  unsigned dg = out_deg[v];
  if (dg > 0u){
    int slot = (int)atomicAdd(&ctr[0], 1u);
    alist[slot] = v; node_slot[v] = slot; slot_deg[slot] = (float)dg;
    atomicAdd((float*)&ctr[2], logf((float)dg + 1.0f));
    if (atomicExch(&flag[v], 1u) == 0u){
      int p = (int)atomicAdd(&ctr[3], 1u);
      tlist[p] = v;
    }
  }
}

// ---------------- k_messages: round-robin scan of selected-src edges + message GEMV ----------------
#define MSG_GRID 512
__global__ __launch_bounds__(128) void k_messages(
    const float* hidden, const int* sedges, const int* node_slot, const unsigned* out_deg,
    const float* preW, const float* preb,
    float* s1, float* s2, unsigned* mxb, unsigned* mnb, unsigned* cnt, const unsigned* ctr){
  int ns = (int)ctr[1];
  int tid = threadIdx.x;
  int bid = blockIdx.x;
  __shared__ int qs[128], qd[128], qsl[128];
  __shared__ int qn_sh;
  __shared__ float sdl[4][Dd], ssl[4][Dd];
  __shared__ int dsl[4];
  float pb = preb[tid];
  int kmax = (ns - bid + MSG_GRID - 1) / MSG_GRID;   // candidates for this block
  if (bid >= ns) kmax = 0;
  for (int k0 = 0; k0 < kmax; k0 += 128){
    if (tid == 0) qn_sh = 0;
    __syncthreads();
    int k = k0 + tid;
    if (k < kmax){
      int j = bid + k*MSG_GRID;
      int dv = sedges[2*j+1];
      if (out_deg[dv] > 0u){
        int slot = node_slot[dv];
        int p = atomicAdd(&qn_sh, 1);
        qs[p] = sedges[2*j]; qd[p] = dv; qsl[p] = slot;
        atomicAdd(&cnt[slot], 1u);
      }
    }
    __syncthreads();
    int nq = qn_sh;
    for (int q0 = 0; q0 < nq; q0 += 4){
      int nv = nq - q0; if (nv > 4) nv = 4;
      if (tid < 4) dsl[tid] = qsl[q0 + ((tid < nv) ? tid : 0)];
      #pragma unroll
      for (int e2=0;e2<4;e2++){
        int qq = q0 + ((e2 < nv) ? e2 : 0);
        sdl[e2][tid] = hidden[(size_t)qd[qq]*Dd + tid];
        ssl[e2][tid] = hidden[(size_t)qs[qq]*Dd + tid];
      }
      __syncthreads();
      float a[4] = {pb, pb, pb, pb};
      #pragma unroll 4
      for (int kk=0;kk<Dd;kk++){
        float w0 = preW[kk*Dd + tid];
        float w1 = preW[(Dd+kk)*Dd + tid];
        #pragma unroll
        for (int e2=0;e2<4;e2++) a[e2] += sdl[e2][kk]*w0 + ssl[e2][kk]*w1;
      }
      for (int e2=0;e2<nv;e2++){
        int dslot = dsl[e2];
        atomicAdd(&s1[dslot*Dd + tid], a[e2]);
        atomicAdd(&s2[dslot*Dd + tid], a[e2]*a[e2]);
        atomicMax(&mxb[dslot*Dd + tid], encf(a[e2]));
        atomicMin(&mnb[dslot*Dd + tid], encf(a[e2]));
      }
      __syncthreads();
    }
  }
}

// ---------------- k_post (round-4, unchanged) ----------------
__global__ __launch_bounds__(512) void k_post(
    const unsigned* cnt, const float* s1, const float* s2,
    const unsigned* mxb, const unsigned* mnb, const float* slot_deg,
    const float* postW, float* tpart, const unsigned* ctr){
  int na = (int)ctr[0];
  int bid = blockIdx.x;
  int tile = bid & 63, ch = bid >> 6;
  if (tile*32 >= na) return;
  float logsum = __uint_as_float(ctr[2]);
  float avg = (logsum + (float)(BN - na)*LN2F) / (float)BN;
  __shared__ float lb[32*136];
  __shared__ float wbuf[3*16*128];
  __shared__ float sden[32];
  __shared__ unsigned shas[32];
  int tid = threadIdx.x;
  if (tid < 32){
    unsigned c = cnt[tile*32 + tid];
    sden[tid] = fmaxf((float)c, 1.0f);
    shas[tid] = c;
  }
  __syncthreads();
  for (int idx = tid; idx < 32*Dd; idx += 512){
    int sl = idx >> 7, kk = idx & 127;
    int gi = (tile*32 + sl)*Dd + kk;
    float den = sden[sl];
    float val;
    if (ch == 0)      val = s1[gi]/den;
    else if (ch == 1) val = shas[sl] ? decf(mxb[gi]) : 0.f;
    else if (ch == 2) val = shas[sl] ? decf(mnb[gi]) : 0.f;
    else {
      float mv = s1[gi]/den;
      float var = s2[gi]/den - mv*mv;
      val = sqrtf(fmaxf(var, 0.f) + EPSV);
    }
    lb[sl*136 + kk] = val;
  }
  int cg = tid & 31, rg = tid >> 5;
  int c0 = cg*4;
  float a0[2][4], a1[2][4], a2[2][4];
  #pragma unroll
  for (int i=0;i<2;i++)
    #pragma unroll
    for (int j=0;j<4;j++){ a0[i][j]=0.f; a1[i][j]=0.f; a2[i][j]=0.f; }
  for (int chunk = 0; chunk < 8; ++chunk){
    #pragma unroll
    for (int i = 0; i < 3; ++i){
      int f = tid + i*512;
      int q = f >> 9, r = f & 511;
      int kk = r >> 5, c4 = r & 31;
      int grow = q*512 + ch*128 + chunk*16 + kk;
      ((float4*)wbuf)[f] = *(const float4*)(postW + (size_t)grow*Dd + c4*4);
    }
    __syncthreads();
    #pragma unroll
    for (int k4 = 0; k4 < 4; ++k4){
      float4 av0 = *(const float4*)&lb[(rg*2+0)*136 + chunk*16 + k4*4];
      float4 av1 = *(const float4*)&lb[(rg*2+1)*136 + chunk*16 + k4*4];
      #pragma unroll
      for (int j = 0; j < 4; ++j){
        int kk = k4*4 + j;
        float4 w0 = *(const float4*)&wbuf[kk*128 + c0];
        float4 w1 = *(const float4*)&wbuf[(16+kk)*128 + c0];
        float4 w2 = *(const float4*)&wbuf[(32+kk)*128 + c0];
        float av[2] = { (&av0.x)[j], (&av1.x)[j] };
        #pragma unroll
        for (int i=0;i<2;i++){
          float a = av[i];
          a0[i][0] += a*w0.x; a0[i][1] += a*w0.y; a0[i][2] += a*w0.z; a0[i][3] += a*w0.w;
          a1[i][0] += a*w1.x; a1[i][1] += a*w1.y; a1[i][2] += a*w1.z; a1[i][3] += a*w1.w;
          a2[i][0] += a*w2.x; a2[i][1] += a*w2.y; a2[i][2] += a*w2.z; a2[i][3] += a*w2.w;
        }
      }
    }
    __syncthreads();
  }
  #pragma unroll
  for (int i=0;i<2;i++){
    int slot = tile*32 + rg*2 + i;
    if (slot < na){
      float dg = slot_deg[slot];
      float logd = logf(dg + 1.f);
      float al = logd/avg, be = avg/logd;
      float4 r;
      r.x = a0[i][0] + al*a1[i][0] + be*a2[i][0];
      r.y = a0[i][1] + al*a1[i][1] + be*a2[i][1];
      r.z = a0[i][2] + al*a1[i][2] + be*a2[i][2];
      r.w = a0[i][3] + al*a1[i][3] + be*a2[i][3];
      *(float4*)(tpart + (size_t)ch*MAXACT*Dd + (size_t)slot*Dd + c0) = r;
    }
  }
}

// ---------------- k_out_resid (round-4, unchanged) ----------------
__global__ __launch_bounds__(256) void k_out_resid(
    const float* tpart, const int* alist, const float* outW, const float* outb,
    const float* postb, float* hidden, const unsigned* ctr){
  int na = (int)ctr[0];
  int tile = blockIdx.x;
  if (tile*32 >= na) return;
  __shared__ float tr[32*136];
  __shared__ float wbuf[16*128];
  int tid = threadIdx.x;
  for (int idx = tid; idx < 32*Dd; idx += 256){
    int sl = idx >> 7, kk = idx & 127;
    size_t o = (size_t)(tile*32 + sl)*Dd + kk;
    tr[sl*136 + kk] = tpart[o] + tpart[(size_t)MAXACT*Dd + o]
                    + tpart[(size_t)2*MAXACT*Dd + o] + tpart[(size_t)3*MAXACT*Dd + o]
                    + postb[kk];
  }
  int cg = tid & 31, rg = tid >> 5;
  int c0 = cg*4;
  float4 ob = *(const float4*)(outb + c0);
  float acc[4][4];
  #pragma unroll
  for (int r=0;r<4;r++){ acc[r][0]=ob.x; acc[r][1]=ob.y; acc[r][2]=ob.z; acc[r][3]=ob.w; }
  for (int chunk = 0; chunk < 8; ++chunk){
    #pragma unroll
    for (int i = 0; i < 2; ++i){
      int f = tid + i*256;
      int kk = f >> 5, c4 = f & 31;
      ((float4*)wbuf)[f] = *(const float4*)(outW + (size_t)(chunk*16 + kk)*Dd + c4*4);
    }
    __syncthreads();
    #pragma unroll
    for (int k4 = 0; k4 < 4; ++k4){
      float4 av[4];
      #pragma unroll
      for (int r=0;r<4;r++)
        av[r] = *(const float4*)&tr[(rg*4+r)*136 + chunk*16 + k4*4];
      #pragma unroll
      for (int j = 0; j < 4; ++j){
        float4 w = *(const float4*)&wbuf[(k4*4+j)*128 + c0];
        #pragma unroll
        for (int r=0;r<4;r++){
          float a = (&av[r].x)[j];
          acc[r][0] += a*w.x; acc[r][1] += a*w.y; acc[r][2] += a*w.z; acc[r][3] += a*w.w;
        }
      }
    }
    __syncthreads();
  }
  #pragma unroll
  for (int r=0;r<4;r++){
    int slot = tile*32 + rg*4 + r;
    if (slot < na){
      int v = alist[slot];
      float* hp = hidden + (size_t)v*Dd + c0;
      float4 h4 = *(float4*)hp;
      h4.x += acc[r][0]; h4.y += acc[r][1]; h4.z += acc[r][2]; h4.w += acc[r][3];
      *(float4*)hp = h4;
    }
  }
}

// ---------------- k_score: touched-list scoring; optional direct-out ----------------
__global__ __launch_bounds__(256) void k_score(
    const float* hidden, const float* cvec, const float* linW,
    const float* m1W, const float* m1b, const float* m2W, const float* m2b,
    const int* tlist, const unsigned* ctr, float* score,
    const int* ovr, int ovr_n, float* outdest){
  int nt = (ovr_n > 0) ? ovr_n : (int)ctr[3];
  const int* list = (ovr_n > 0) ? ovr : tlist;
  int nb = blockIdx.x * 32;
  if (nb >= nt) return;
  __shared__ float sh[32*Dd];
  __shared__ float sx[32*Dd];
  __shared__ float sc[2*Dd];
  __shared__ int   sv[32];
  __shared__ float red[32*33];
  int tid = threadIdx.x;
  if (tid < 32){
    int idx = nb + tid;
    sv[tid] = (idx < nt) ? list[idx] : list[nb];
  }
  sc[tid] = cvec[tid];
  __syncthreads();
  for (int q = tid; q < 32*32; q += 256){
    int row = q >> 5, f4 = q & 31;
    ((float4*)sh)[row*32 + f4] = ((const float4*)(hidden + (size_t)sv[row]*Dd))[f4];
  }
  __syncthreads();
  int cg = tid & 31, rg = tid >> 5;
  int c0 = cg*4;
  float acc[4][4];
  #pragma unroll
  for (int i=0;i<4;i++){ acc[i][0]=0.f; acc[i][1]=0.f; acc[i][2]=0.f; acc[i][3]=0.f; }
  for (int k4=0;k4<32;k4++){
    float4 av[4];
    #pragma unroll
    for (int i=0;i<4;i++) av[i] = ((float4*)sh)[(rg*4+i)*32 + k4];
    #pragma unroll
    for (int j=0;j<4;j++){
      float4 w = *(const float4*)(linW + (size_t)(k4*4+j)*Dd + c0);
      #pragma unroll
      for (int i=0;i<4;i++){
        float a = (&av[i].x)[j];
        acc[i][0] += a*w.x; acc[i][1] += a*w.y; acc[i][2] += a*w.z; acc[i][3] += a*w.w;
      }
    }
  }
  #pragma unroll
  for (int i=0;i<4;i++){
    int row = rg*4 + i;
    int bb = (sv[row] >= Nn) ? 1 : 0;
    float4 cv = *(float4*)&sc[bb*Dd + c0];
    float4 hv = ((float4*)sh)[row*32 + cg];
    float4 x;
    x.x = (acc[i][0] + cv.x)*hv.x;
    x.y = (acc[i][1] + cv.y)*hv.y;
    x.z = (acc[i][2] + cv.z)*hv.z;
    x.w = (acc[i][3] + cv.w)*hv.w;
    ((float4*)sx)[row*32 + cg] = x;
  }
  __syncthreads();
  #pragma unroll
  for (int i=0;i<4;i++){ acc[i][0]=0.f; acc[i][1]=0.f; acc[i][2]=0.f; acc[i][3]=0.f; }
  for (int k4=0;k4<32;k4++){
    float4 av[4];
    #pragma unroll
    for (int i=0;i<4;i++) av[i] = ((float4*)sx)[(rg*4+i)*32 + k4];
    #pragma unroll
    for (int j=0;j<4;j++){
      float4 w = *(const float4*)(m1W + (size_t)(k4*4+j)*Dd + c0);
      #pragma unroll
      for (int i=0;i<4;i++){
        float a = (&av[i].x)[j];
        acc[i][0] += a*w.x; acc[i][1] += a*w.y; acc[i][2] += a*w.z; acc[i][3] += a*w.w;
      }
    }
  }
  float4 mb = *(const float4*)(m1b + c0);
  float4 mw = *(const float4*)(m2W + c0);
  #pragma unroll
  for (int i=0;i<4;i++){
    float p0 = fmaxf(acc[i][0]+mb.x, 0.f)*mw.x;
    float p1 = fmaxf(acc[i][1]+mb.y, 0.f)*mw.y;
    float p2 = fmaxf(acc[i][2]+mb.z, 0.f)*mw.z;
    float p3 = fmaxf(acc[i][3]+mb.w, 0.f)*mw.w;
    red[(rg*4+i)*33 + cg] = p0+p1+p2+p3;
  }
  __syncthreads();
  if (tid < 32){
    float s = m2b[0];
    for (int g=0; g<32; g++) s += red[tid*33 + g];
    if (nb + tid < nt){
      if (outdest) outdest[nb + tid] = s;
      else         score[sv[tid]] = s;
    }
  }
}

// ---------------- launch ----------------
extern "C" void kernel_launch(void* const* d_in, const int* in_sizes, int n_in,
                              void* d_out, int out_size, void* d_ws, size_t ws_size,
                              hipStream_t stream){
  const int*   h_index       = (const int*)d_in[0];
  const int*   r_index       = (const int*)d_in[1];
  const int*   t_index       = (const int*)d_in[2];
  const float* hidden_states = (const float*)d_in[3];
  const int*   edge_index    = (const int*)d_in[4];
  const float* rel_embedding = (const float*)d_in[5];
  const float* lin_W  = (const float*)d_in[6];
  const float* lin_b  = (const float*)d_in[7];
  const float* m1_W   = (const float*)d_in[8];
  const float* m1_b   = (const float*)d_in[9];
  const float* m2_W   = (const float*)d_in[10];
  const float* m2_b   = (const float*)d_in[11];
  const float* pre_W  = (const float*)d_in[12];
  const float* pre_b  = (const float*)d_in[13];
  const float* post_W = (const float*)d_in[14];
  const float* post_b = (const float*)d_in[15];
  const float* out_W  = (const float*)d_in[16];
  const float* out_b  = (const float*)d_in[17];

  char* ws = (char*)d_ws;
  float*    hidden   = (float*)(ws + HID_OFF);
  float*    score    = (float*)(ws + SCORE_OFF);
  float*    cvec     = (float*)(ws + CVEC_OFF);
  int*      hdr      = (int*)(ws + HDR_OFF);
  unsigned long long* thr = (unsigned long long*)(ws + THR_OFF);
  unsigned* out_deg  = (unsigned*)(ws + DEG_OFF);
  int*      node_slot= (int*)(ws + SLOT_OFF);
  unsigned* cnt      = (unsigned*)(ws + CNT_OFF);
  float*    slot_deg = (float*)(ws + SDEG_OFF);
  float*    s1       = (float*)(ws + S1_OFF);
  float*    s2       = (float*)(ws + S2_OFF);
  unsigned* mxb      = (unsigned*)(ws + MXB_OFF);
  unsigned* mnb      = (unsigned*)(ws + MNB_OFF);
  float*    tpart    = (float*)(ws + TPART_OFF);
  int*      alist    = (int*)(ws + ALIST_OFF);
  unsigned* flag     = (unsigned*)(ws + FLAG_OFF);
  int*      tlist    = (int*)(ws + TLIST_OFF);
  int*      sedges   = (int*)(ws + EDGE_OFF);
  unsigned* ctr      = (unsigned*)(ws + CTR_OFF);

  k_init<<<2048, 256, 0, stream>>>(h_index, r_index, t_index, hidden_states, rel_embedding,
                                   lin_W, lin_b, m1_W, m1_b, m2_W, m2_b,
                                   hdr, cvec, hidden, score, flag, tlist, ctr);
  for (int l = 0; l < Ll; ++l){
    const float* preWl  = pre_W  + (size_t)l*2*Dd*Dd;
    const float* prebl  = pre_b  + (size_t)l*Dd;
    const float* postWl = post_W + (size_t)l*12*Dd*Dd;
    const float* postbl = post_b + (size_t)l*Dd;
    const float* outWl  = out_W  + (size_t)l*Dd*Dd;
    const float* outbl  = out_b  + (size_t)l*Dd;

    k_selz<<<512, 256, 0, stream>>>(score, tlist, ctr, thr, out_deg, s1, s2, mxb, mnb, cnt);
    k_degree<<<(Ee + 255)/256, 256, 0, stream>>>(edge_index, score, thr, out_deg, sedges, ctr);
    k_active<<<(BN + 255)/256, 256, 0, stream>>>(out_deg, node_slot, alist, slot_deg,
                                                 ctr, flag, tlist);
    k_messages<<<MSG_GRID, 128, 0, stream>>>(hidden, sedges, node_slot, out_deg,
                                             preWl, prebl, s1, s2, mxb, mnb, cnt, ctr);
    k_post<<<256, 512, 0, stream>>>(cnt, s1, s2, mxb, mnb, slot_deg, postWl, tpart, ctr);
    k_out_resid<<<MAXACT/32, 256, 0, stream>>>(tpart, alist, outWl, outbl, postbl,
                                               hidden, ctr);
    if (l < Ll-1){
      k_score<<<MAXTOUCH/32, 256, 0, stream>>>(hidden, cvec, lin_W, m1_W, m1_b, m2_W, m2_b,
                                               tlist, ctr, score, tlist, 0, nullptr);
    } else {
      k_score<<<1, 256, 0, stream>>>(hidden, cvec, lin_W, m1_W, m1_b, m2_W, m2_b,
                                     tlist, ctr, score, hdr + 4, Bq*NEG, (float*)d_out);
    }
  }
}